// Round 4
// baseline (239.750 us; speedup 1.0000x reference)
//
#include <hip/hip_runtime.h>
#include <stdint.h>

#define DIM 512
#define NHEADS 8
#define HDIM 64
#define NBINS 961
#define BATCH 64
#define SEQ 256
#define NTOK (BATCH*SEQ)            // 16384
#define BHND (BATCH*NHEADS*SEQ*HDIM) // 8388608 elements per q/k/v tensor

using bf16x8 = __attribute__((ext_vector_type(8))) short;
using f32x4  = __attribute__((ext_vector_type(4))) float;

__device__ __forceinline__ unsigned short f2bf(float f) {
  unsigned u = __float_as_uint(f);
  u += 0x7FFF + ((u >> 16) & 1);   // round-to-nearest-even
  return (unsigned short)(u >> 16);
}

__device__ __forceinline__ void async16(const void* g, void* lds) {
  __builtin_amdgcn_global_load_lds(
      (const __attribute__((address_space(1))) unsigned int*)g,
      (__attribute__((address_space(3))) unsigned int*)lds,
      16, 0, 0);
}

// ---------------- prep kernels ----------------

__global__ void cast_kernel(const float* __restrict__ in,
                            unsigned short* __restrict__ out, int n4) {
  int i = blockIdx.x * 256 + threadIdx.x;
  if (i >= n4) return;
  float4 f = reinterpret_cast<const float4*>(in)[i];
  ushort4 o;
  o.x = f2bf(f.x); o.y = f2bf(f.y); o.z = f2bf(f.z); o.w = f2bf(f.w);
  reinterpret_cast<ushort4*>(out)[i] = o;
}

// bias stored PERMUTED for vectorized attn reads:
// pos = h*65536 + n*256 + (m&15)*16 + (m>>4)  ==> lane reads 16 consecutive
// floats at l15*16 to get columns {l15, l15+16, ..., l15+240}.
__global__ void bias_kernel(const int* __restrict__ idx,
                            const float* __restrict__ rpb,
                            float* __restrict__ bf) {
  int i = blockIdx.x * 256 + threadIdx.x;   // [0, 8*65536)
  if (i >= NHEADS * SEQ * SEQ) return;
  int h = i >> 16;
  int r = i & 65535;
  int n = r >> 8, m = r & 255;
  bf[(size_t)h * 65536 + n * 256 + (m & 15) * 16 + (m >> 4)] = rpb[h * NBINS + idx[r]];
}

// ---------------- GEMM: C = A(M x 512) * B^T(N x 512) + bias ----------------
// 128x128 tile, BK=32, depth-3 LDS ring (48 KB), one barrier per K-step,
// vmcnt(4) counted gate, XOR chunk swizzle (source + read), 3 blocks/CU.
// EPI 0: scatter into q/k/v (B,H,N,D) bf16.  EPI 1: fp32 out row-major + bias.

__device__ __forceinline__ void stage_tile(const unsigned short* __restrict__ A,
                                           const unsigned short* __restrict__ Bw,
                                           char* slot, int T,
                                           int m0, int n0, int t) {
  const int kk = T * 32;
  const int wv64 = (t >> 6) << 6;
#pragma unroll
  for (int i = 0; i < 2; ++i) {
    int c = t + i * 256;               // 16B chunk id in [0,512)
    int row = c >> 2, ch = c & 3;
    int sch = ch ^ ((row >> 1) & 3);   // source swizzle (linear LDS dest)
    const unsigned short* ga = A + (size_t)(m0 + row) * 512 + kk + sch * 8;
    async16(ga, slot + (i * 256 + wv64) * 16);
    const unsigned short* gb = Bw + (size_t)(n0 + row) * 512 + kk + sch * 8;
    async16(gb, slot + 8192 + (i * 256 + wv64) * 16);
  }
}

template<int EPI>
__global__ __launch_bounds__(256, 3) void gemm_bt(
    const unsigned short* __restrict__ A,
    const unsigned short* __restrict__ Bw,
    const float* __restrict__ bias,
    void* __restrict__ outp) {
  __shared__ char gsm[49152];          // 3 ring slots x (8KB A + 8KB B)
  const int t = threadIdx.x;
  const int lane = t & 63;
  const int l15 = lane & 15, lg = lane >> 4;
  const int m0 = blockIdx.x * 128, n0 = blockIdx.y * 128;
  const int wv = t >> 6;
  const int wm = wv & 1, wn = wv >> 1;

  f32x4 acc[4][4];
  const f32x4 fz = {0.f, 0.f, 0.f, 0.f};
#pragma unroll
  for (int a = 0; a < 4; ++a)
#pragma unroll
    for (int b = 0; b < 4; ++b) acc[a][b] = fz;

  stage_tile(A, Bw, gsm,         0, m0, n0, t);
  stage_tile(A, Bw, gsm + 16384, 1, m0, n0, t);

  int cur = 0;                         // slot of tile T
#pragma unroll 1
  for (int T = 0; T < 16; ++T) {
    if (T < 15) asm volatile("s_waitcnt vmcnt(4)" ::: "memory");
    else        asm volatile("s_waitcnt vmcnt(0)" ::: "memory");
    __builtin_amdgcn_s_barrier();      // tile T resident; all slot reads of T-1 done
    __builtin_amdgcn_sched_barrier(0);

    if (T < 14) {                      // stage T+2 into slot (T+2)%3 == (T-1)%3
      int dst = cur + 2; if (dst >= 3) dst -= 3;
      stage_tile(A, Bw, gsm + dst * 16384, T + 2, m0, n0, t);
    }
    __builtin_amdgcn_sched_barrier(0);

    char* As = gsm + cur * 16384;
    char* Bs = As + 8192;
    bf16x8 af[4], bfr[4];
#pragma unroll
    for (int x = 0; x < 4; ++x) {
      int ra = wm * 64 + x * 16 + l15;
      af[x]  = *(const bf16x8*)(As + ra * 64 + ((lg ^ ((ra >> 1) & 3)) * 16));
      int rb = wn * 64 + x * 16 + l15;
      bfr[x] = *(const bf16x8*)(Bs + rb * 64 + ((lg ^ ((rb >> 1) & 3)) * 16));
    }
    asm volatile("s_waitcnt lgkmcnt(0)" ::: "memory");
    __builtin_amdgcn_sched_barrier(0);

    __builtin_amdgcn_s_setprio(1);
#pragma unroll
    for (int mi = 0; mi < 4; ++mi)
#pragma unroll
      for (int ni = 0; ni < 4; ++ni)
        acc[mi][ni] = __builtin_amdgcn_mfma_f32_16x16x32_bf16(af[mi], bfr[ni], acc[mi][ni], 0, 0, 0);
    __builtin_amdgcn_s_setprio(0);

    cur = cur + 1; if (cur >= 3) cur -= 3;
  }

#pragma unroll
  for (int mi = 0; mi < 4; ++mi)
#pragma unroll
    for (int ni = 0; ni < 4; ++ni)
#pragma unroll
      for (int r = 0; r < 4; ++r) {
        int row = m0 + wm * 64 + mi * 16 + lg * 4 + r;
        int col = n0 + wn * 64 + ni * 16 + l15;
        float v = acc[mi][ni][r] + bias[col];
        if (EPI == 0) {
          int which = col >> 9, hd = col & 511;
          int b = row >> 8, n = row & 255;
          ((unsigned short*)outp)[(size_t)which * BHND +
              (((size_t)(b * NHEADS + (hd >> 6)) * SEQ + n) * HDIM) + (hd & 63)] = f2bf(v);
        } else {
          ((float*)outp)[(size_t)row * 512 + col] = v;
        }
      }
}

// ---------------- fused attention: one block per (b,h) ----------------
// K-fragments read straight from global (L2-resident); only V^T and P in LDS
// (64 KB total -> 2 blocks/CU).

__global__ __launch_bounds__(512, 4) void attn_kernel(
    const unsigned short* __restrict__ qb,
    const unsigned short* __restrict__ kb,
    const unsigned short* __restrict__ vb,
    const float* __restrict__ biasf,
    unsigned short* __restrict__ aout) {
  extern __shared__ char smem[];
  char* v_s = smem;                     // 32 KB: vT [64 d][256 keys] bf16, key+dhi swizzle
  const int t = threadIdx.x, lane = t & 63, w = t >> 6;
  const int l15 = lane & 15, lg = lane >> 4;
  char* P_s = smem + 32768 + w * 4096;  // per-wave [32 rows][64 keys] bf16, swizzled
  const int bh = blockIdx.x;
  const int h = bh & 7;
  const int b = bh >> 3;
  const size_t base = (size_t)bh * (SEQ * HDIM);

  // stage V transposed (vT[d][key]); swizzle spreads banks over key AND d>>3
#pragma unroll
  for (int i = 0; i < 4; ++i) {
    int c = i * 512 + t;
    int key = c >> 3, d0 = (c & 7) * 8;
    bf16x8 val = *(const bf16x8*)(vb + base + (size_t)c * 8);
#pragma unroll
    for (int j = 0; j < 8; ++j) {
      int d = d0 + j;
      int term = (((d & 7) ^ ((d >> 3) & 7)) << 4);
      *(short*)(v_s + d * 512 + ((key * 2) ^ term)) = val[j];
    }
  }
  // q fragments straight from global (L2-resident)
  bf16x8 qa[2][2];
#pragma unroll
  for (int rf = 0; rf < 2; ++rf)
#pragma unroll
    for (int ks = 0; ks < 2; ++ks)
      qa[rf][ks] = *(const bf16x8*)(qb + base + (size_t)(w * 32 + rf * 16 + l15) * 64 + ks * 32 + lg * 8);

  // scores: S = q . k^T, K fragments from global
  const unsigned short* kbase = kb + base;
  f32x4 accs[2][16];
  const f32x4 fz = {0.f, 0.f, 0.f, 0.f};
#pragma unroll
  for (int a = 0; a < 2; ++a)
#pragma unroll
    for (int c = 0; c < 16; ++c) accs[a][c] = fz;
#pragma unroll
  for (int cf = 0; cf < 16; ++cf) {
    int key = cf * 16 + l15;
#pragma unroll
    for (int ks = 0; ks < 2; ++ks) {
      bf16x8 kf = *(const bf16x8*)(kbase + (size_t)key * 64 + ks * 32 + lg * 8);
      accs[0][cf] = __builtin_amdgcn_mfma_f32_16x16x32_bf16(qa[0][ks], kf, accs[0][cf], 0, 0, 0);
      accs[1][cf] = __builtin_amdgcn_mfma_f32_16x16x32_bf16(qa[1][ks], kf, accs[1][cf], 0, 0, 0);
    }
  }

  // scale + rel-pos bias (permuted layout -> 4x float4 per row)
  const float* bh_ptr = biasf + (size_t)h * 65536;
#pragma unroll
  for (int rf = 0; rf < 2; ++rf)
#pragma unroll
    for (int r = 0; r < 4; ++r) {
      int n = w * 32 + rf * 16 + lg * 4 + r;
      const f32x4* bp = (const f32x4*)(bh_ptr + n * 256 + l15 * 16);
      f32x4 b0 = bp[0], b1 = bp[1], b2 = bp[2], b3 = bp[3];
#pragma unroll
      for (int cf = 0; cf < 16; ++cf) {
        float bb = (cf < 4) ? b0[cf] : (cf < 8) ? b1[cf - 4] : (cf < 12) ? b2[cf - 8] : b3[cf - 12];
        accs[rf][cf][r] = accs[rf][cf][r] * 0.125f + bb;
      }
    }

  // softmax across 256 keys (16 in-lane x 16 lanes)
  float pinv[2][4];
#pragma unroll
  for (int rf = 0; rf < 2; ++rf)
#pragma unroll
    for (int r = 0; r < 4; ++r) {
      float m = -1e30f;
#pragma unroll
      for (int cf = 0; cf < 16; ++cf) m = fmaxf(m, accs[rf][cf][r]);
#pragma unroll
      for (int off = 1; off < 16; off <<= 1) m = fmaxf(m, __shfl_xor(m, off, 64));
      float s = 0.f;
#pragma unroll
      for (int cf = 0; cf < 16; ++cf) {
        float p = __expf(accs[rf][cf][r] - m);
        accs[rf][cf][r] = p;
        s += p;
      }
#pragma unroll
      for (int off = 1; off < 16; off <<= 1) s += __shfl_xor(s, off, 64);
      pinv[rf][r] = 1.0f / s;
    }

  __syncthreads();   // V_s writes complete (hidden under QK^T + softmax)

  // PV: out = P . V, P staged per-wave through LDS in 64-key chunks
  f32x4 acco[2][4];
#pragma unroll
  for (int a = 0; a < 2; ++a)
#pragma unroll
    for (int c2 = 0; c2 < 4; ++c2) acco[a][c2] = fz;

  for (int ch = 0; ch < 4; ++ch) {
#pragma unroll
    for (int rf = 0; rf < 2; ++rf)
#pragma unroll
      for (int cl = 0; cl < 4; ++cl)
#pragma unroll
        for (int r = 0; r < 4; ++r) {
          int rowl = rf * 16 + lg * 4 + r;
          int ml = cl * 16 + l15;
          float p = accs[rf][ch * 4 + cl][r] * pinv[rf][r];
          *(short*)(P_s + rowl * 128 + ((ml * 2) ^ ((rowl & 7) << 4))) = (short)f2bf(p);
        }
#pragma unroll
    for (int ks = 0; ks < 2; ++ks) {
      bf16x8 pa[2];
#pragma unroll
      for (int rf = 0; rf < 2; ++rf) {
        int row = rf * 16 + l15;
        pa[rf] = *(const bf16x8*)(P_s + row * 128 + ((lg * 16 + ks * 64) ^ ((row & 7) << 4)));
      }
      int keyb = (ch * 64 + ks * 32 + lg * 8) * 2;
      __builtin_amdgcn_s_setprio(1);
#pragma unroll
      for (int df = 0; df < 4; ++df) {
        int d = df * 16 + l15;
        int term = (((d & 7) ^ ((d >> 3) & 7)) << 4);
        bf16x8 vf = *(const bf16x8*)(v_s + d * 512 + (keyb ^ term));
        acco[0][df] = __builtin_amdgcn_mfma_f32_16x16x32_bf16(pa[0], vf, acco[0][df], 0, 0, 0);
        acco[1][df] = __builtin_amdgcn_mfma_f32_16x16x32_bf16(pa[1], vf, acco[1][df], 0, 0, 0);
      }
      __builtin_amdgcn_s_setprio(0);
    }
  }

  // write attn output in (b, n, h*64+d) bf16
#pragma unroll
  for (int rf = 0; rf < 2; ++rf)
#pragma unroll
    for (int df = 0; df < 4; ++df)
#pragma unroll
      for (int r = 0; r < 4; ++r) {
        int n = w * 32 + rf * 16 + lg * 4 + r;
        int d = df * 16 + l15;
        aout[((size_t)(b * SEQ + n)) * DIM + h * HDIM + d] = f2bf(acco[rf][df][r]);
      }
}

// ---------------- launch ----------------

extern "C" void kernel_launch(void* const* d_in, const int* in_sizes, int n_in,
                              void* d_out, int out_size, void* d_ws, size_t ws_size,
                              hipStream_t stream) {
  const float* x      = (const float*)d_in[0];
  const int*   rpi    = (const int*)d_in[1];
  const float* qkv_w  = (const float*)d_in[2];
  const float* qkv_b  = (const float*)d_in[3];
  const float* proj_w = (const float*)d_in[4];
  const float* proj_b = (const float*)d_in[5];
  const float* rpb    = (const float*)d_in[6];

  char* ws = (char*)d_ws;
  unsigned short* xb    = (unsigned short*)ws;                  // 16,777,216 B
  unsigned short* wqkv  = (unsigned short*)(ws + 16777216);     //  1,572,864 B
  unsigned short* wproj = (unsigned short*)(ws + 18350080);     //    524,288 B
  float*          biasf = (float*)         (ws + 18874368);     //  2,097,152 B
  unsigned short* qkvb  = (unsigned short*)(ws + 20971520);     // 50,331,648 B (q,k,v)
  unsigned short* aoutb = (unsigned short*)(ws + 71303168);     // 16,777,216 B
  // total ws use: 88,080,384 B

  cast_kernel<<<8192, 256, 0, stream>>>(x, xb, 2097152);
  cast_kernel<<<768, 256, 0, stream>>>(qkv_w, wqkv, 196608);
  cast_kernel<<<256, 256, 0, stream>>>(proj_w, wproj, 65536);
  bias_kernel<<<2048, 256, 0, stream>>>(rpi, rpb, biasf);

  dim3 g1(128, 12);
  gemm_bt<0><<<g1, 256, 0, stream>>>(xb, wqkv, qkv_b, (void*)qkvb);

  attn_kernel<<<512, 512, 65536, stream>>>(qkvb, qkvb + BHND, qkvb + 2 * (size_t)BHND,
                                           biasf, aoutb);

  dim3 g2(128, 4);
  gemm_bt<1><<<g2, 256, 0, stream>>>(aoutb, wproj, proj_b, d_out);
}

// Round 5
// 110.514 us; speedup vs baseline: 2.1694x; 2.1694x over previous
//
#include <hip/hip_runtime.h>
#include <stdint.h>

#define DIM 512
#define NHEADS 8
#define HDIM 64
#define NBINS 961
#define BATCH 64
#define SEQ 256
#define NTOK (BATCH*SEQ)            // 16384
#define BHND (BATCH*NHEADS*SEQ*HDIM) // 8388608 elements per q/k/v tensor

using bf16x8 = __attribute__((ext_vector_type(8))) short;
using f32x4  = __attribute__((ext_vector_type(4))) float;

__device__ __forceinline__ unsigned short f2bf(float f) {
  unsigned u = __float_as_uint(f);
  u += 0x7FFF + ((u >> 16) & 1);   // round-to-nearest-even
  return (unsigned short)(u >> 16);
}

__device__ __forceinline__ void async16(const void* g, void* lds) {
  __builtin_amdgcn_global_load_lds(
      (const __attribute__((address_space(1))) unsigned int*)g,
      (__attribute__((address_space(3))) unsigned int*)lds,
      16, 0, 0);
}

// ---------------- prep kernels ----------------

__global__ void cast_kernel(const float* __restrict__ in,
                            unsigned short* __restrict__ out, int n4) {
  int i = blockIdx.x * 256 + threadIdx.x;
  if (i >= n4) return;
  float4 f = reinterpret_cast<const float4*>(in)[i];
  ushort4 o;
  o.x = f2bf(f.x); o.y = f2bf(f.y); o.z = f2bf(f.z); o.w = f2bf(f.w);
  reinterpret_cast<ushort4*>(out)[i] = o;
}

// bias stored PERMUTED for vectorized attn reads:
// pos = h*65536 + n*256 + (m&15)*16 + (m>>4)  ==> lane reads 16 consecutive
// floats at l15*16 to get columns {l15, l15+16, ..., l15+240}.
__global__ void bias_kernel(const int* __restrict__ idx,
                            const float* __restrict__ rpb,
                            float* __restrict__ bf) {
  int i = blockIdx.x * 256 + threadIdx.x;   // [0, 8*65536)
  if (i >= NHEADS * SEQ * SEQ) return;
  int h = i >> 16;
  int r = i & 65535;
  int n = r >> 8, m = r & 255;
  bf[(size_t)h * 65536 + n * 256 + (m & 15) * 16 + (m >> 4)] = rpb[h * NBINS + idx[r]];
}

// ---------------- GEMM: C = A(M x 512) * B^T(N x 512) + bias ----------------
// 128x128 tile, BK=32, depth-3 LDS ring (48 KB), one barrier per K-step,
// vmcnt(4) counted gate, XOR chunk swizzle (source + read), 3 blocks/CU.
// EPI 0: scatter into q/k/v (B,H,N,D) bf16.  EPI 1: fp32 out row-major + bias.

__device__ __forceinline__ void stage_tile(const unsigned short* __restrict__ A,
                                           const unsigned short* __restrict__ Bw,
                                           char* slot, int T,
                                           int m0, int n0, int t) {
  const int kk = T * 32;
  const int wv64 = (t >> 6) << 6;
#pragma unroll
  for (int i = 0; i < 2; ++i) {
    int c = t + i * 256;               // 16B chunk id in [0,512)
    int row = c >> 2, ch = c & 3;
    int sch = ch ^ ((row >> 1) & 3);   // source swizzle (linear LDS dest)
    const unsigned short* ga = A + (size_t)(m0 + row) * 512 + kk + sch * 8;
    async16(ga, slot + (i * 256 + wv64) * 16);
    const unsigned short* gb = Bw + (size_t)(n0 + row) * 512 + kk + sch * 8;
    async16(gb, slot + 8192 + (i * 256 + wv64) * 16);
  }
}

template<int EPI>
__global__ __launch_bounds__(256, 3) void gemm_bt(
    const unsigned short* __restrict__ A,
    const unsigned short* __restrict__ Bw,
    const float* __restrict__ bias,
    void* __restrict__ outp) {
  __shared__ char gsm[49152];          // 3 ring slots x (8KB A + 8KB B)
  const int t = threadIdx.x;
  const int lane = t & 63;
  const int l15 = lane & 15, lg = lane >> 4;
  const int m0 = blockIdx.x * 128, n0 = blockIdx.y * 128;
  const int wv = t >> 6;
  const int wm = wv & 1, wn = wv >> 1;

  f32x4 acc[4][4];
  const f32x4 fz = {0.f, 0.f, 0.f, 0.f};
#pragma unroll
  for (int a = 0; a < 4; ++a)
#pragma unroll
    for (int b = 0; b < 4; ++b) acc[a][b] = fz;

  stage_tile(A, Bw, gsm,         0, m0, n0, t);
  stage_tile(A, Bw, gsm + 16384, 1, m0, n0, t);

  int cur = 0;                         // slot of tile T
#pragma unroll 1
  for (int T = 0; T < 16; ++T) {
    if (T < 15) asm volatile("s_waitcnt vmcnt(4)" ::: "memory");
    else        asm volatile("s_waitcnt vmcnt(0)" ::: "memory");
    __builtin_amdgcn_s_barrier();      // tile T resident; all slot reads of T-1 done
    __builtin_amdgcn_sched_barrier(0);

    if (T < 14) {                      // stage T+2 into slot (T+2)%3 == (T-1)%3
      int dst = cur + 2; if (dst >= 3) dst -= 3;
      stage_tile(A, Bw, gsm + dst * 16384, T + 2, m0, n0, t);
    }
    __builtin_amdgcn_sched_barrier(0);

    char* As = gsm + cur * 16384;
    char* Bs = As + 8192;
    bf16x8 af[4], bfr[4];
#pragma unroll
    for (int x = 0; x < 4; ++x) {
      int ra = wm * 64 + x * 16 + l15;
      af[x]  = *(const bf16x8*)(As + ra * 64 + ((lg ^ ((ra >> 1) & 3)) * 16));
      int rb = wn * 64 + x * 16 + l15;
      bfr[x] = *(const bf16x8*)(Bs + rb * 64 + ((lg ^ ((rb >> 1) & 3)) * 16));
    }
    asm volatile("s_waitcnt lgkmcnt(0)" ::: "memory");
    __builtin_amdgcn_sched_barrier(0);

    __builtin_amdgcn_s_setprio(1);
#pragma unroll
    for (int mi = 0; mi < 4; ++mi)
#pragma unroll
      for (int ni = 0; ni < 4; ++ni)
        acc[mi][ni] = __builtin_amdgcn_mfma_f32_16x16x32_bf16(af[mi], bfr[ni], acc[mi][ni], 0, 0, 0);
    __builtin_amdgcn_s_setprio(0);

    cur = cur + 1; if (cur >= 3) cur -= 3;
  }

#pragma unroll
  for (int mi = 0; mi < 4; ++mi)
#pragma unroll
    for (int ni = 0; ni < 4; ++ni)
#pragma unroll
      for (int r = 0; r < 4; ++r) {
        int row = m0 + wm * 64 + mi * 16 + lg * 4 + r;
        int col = n0 + wn * 64 + ni * 16 + l15;
        float v = acc[mi][ni][r] + bias[col];
        if (EPI == 0) {
          int which = col >> 9, hd = col & 511;
          int b = row >> 8, n = row & 255;
          ((unsigned short*)outp)[(size_t)which * BHND +
              (((size_t)(b * NHEADS + (hd >> 6)) * SEQ + n) * HDIM) + (hd & 63)] = f2bf(v);
        } else {
          ((float*)outp)[(size_t)row * 512 + col] = v;
        }
      }
}

// ---------------- fused attention: one block per (b,h) ----------------
// K in LDS (32 KB, XOR-swizzled); V^T in LDS (32 KB); P_s REUSES the K
// region after QK^T (single extra barrier). 64 KB total.

__global__ __launch_bounds__(512, 2) void attn_kernel(
    const unsigned short* __restrict__ qb,
    const unsigned short* __restrict__ kb,
    const unsigned short* __restrict__ vb,
    const float* __restrict__ biasf,
    unsigned short* __restrict__ aout) {
  extern __shared__ char smem[];
  char* k_s = smem;               // 32 KB: [256 keys][64 d] bf16, XOR-swizzled rows
  char* v_s = smem + 32768;       // 32 KB: vT [64 d][256 keys] bf16, key+dhi swizzle
  const int t = threadIdx.x, lane = t & 63, w = t >> 6;
  const int l15 = lane & 15, lg = lane >> 4;
  char* P_s = smem + w * 4096;    // per-wave [32 rows][64 keys] bf16 — reuses k_s
  const int bh = blockIdx.x;
  const int h = bh & 7;
  const int b = bh >> 3;
  const size_t base = (size_t)bh * (SEQ * HDIM);

  // stage K (swizzled row-major)
#pragma unroll
  for (int i = 0; i < 4; ++i) {
    int c = i * 512 + t;            // 16B chunk, 2048 total
    int row = c >> 3, sl = c & 7;
    bf16x8 val = *(const bf16x8*)(kb + base + (size_t)c * 8);
    *(bf16x8*)(k_s + row * 128 + ((sl * 16) ^ ((row & 7) << 4))) = val;
  }
  // stage V transposed (vT[d][key]); swizzle spreads banks over key AND d>>3
#pragma unroll
  for (int i = 0; i < 4; ++i) {
    int c = i * 512 + t;
    int key = c >> 3, d0 = (c & 7) * 8;
    bf16x8 val = *(const bf16x8*)(vb + base + (size_t)c * 8);
#pragma unroll
    for (int j = 0; j < 8; ++j) {
      int d = d0 + j;
      int term = (((d & 7) ^ ((d >> 3) & 7)) << 4);
      *(short*)(v_s + d * 512 + ((key * 2) ^ term)) = val[j];
    }
  }
  // q fragments straight from global (L2-resident)
  bf16x8 qa[2][2];
#pragma unroll
  for (int rf = 0; rf < 2; ++rf)
#pragma unroll
    for (int ks = 0; ks < 2; ++ks)
      qa[rf][ks] = *(const bf16x8*)(qb + base + (size_t)(w * 32 + rf * 16 + l15) * 64 + ks * 32 + lg * 8);
  __syncthreads();

  // scores: S = q . k^T   (wave owns 32 query rows x 256 keys)
  f32x4 accs[2][16];
  const f32x4 fz = {0.f, 0.f, 0.f, 0.f};
#pragma unroll
  for (int a = 0; a < 2; ++a)
#pragma unroll
    for (int c = 0; c < 16; ++c) accs[a][c] = fz;
  __builtin_amdgcn_s_setprio(1);
#pragma unroll
  for (int cf = 0; cf < 16; ++cf) {
    int key = cf * 16 + l15;
#pragma unroll
    for (int ks = 0; ks < 2; ++ks) {
      bf16x8 kf = *(const bf16x8*)(k_s + key * 128 + ((lg * 16 + ks * 64) ^ ((key & 7) << 4)));
      accs[0][cf] = __builtin_amdgcn_mfma_f32_16x16x32_bf16(qa[0][ks], kf, accs[0][cf], 0, 0, 0);
      accs[1][cf] = __builtin_amdgcn_mfma_f32_16x16x32_bf16(qa[1][ks], kf, accs[1][cf], 0, 0, 0);
    }
  }
  __builtin_amdgcn_s_setprio(0);

  // scale + rel-pos bias (permuted layout -> 4x float4 per row)
  const float* bh_ptr = biasf + (size_t)h * 65536;
#pragma unroll
  for (int rf = 0; rf < 2; ++rf)
#pragma unroll
    for (int r = 0; r < 4; ++r) {
      int n = w * 32 + rf * 16 + lg * 4 + r;
      const f32x4* bp = (const f32x4*)(bh_ptr + n * 256 + l15 * 16);
      f32x4 b0 = bp[0], b1 = bp[1], b2 = bp[2], b3 = bp[3];
#pragma unroll
      for (int cf = 0; cf < 16; ++cf) {
        float bb = (cf < 4) ? b0[cf] : (cf < 8) ? b1[cf - 4] : (cf < 12) ? b2[cf - 8] : b3[cf - 12];
        accs[rf][cf][r] = accs[rf][cf][r] * 0.125f + bb;
      }
    }

  // softmax across 256 keys (16 in-lane x 16 lanes)
  float pinv[2][4];
#pragma unroll
  for (int rf = 0; rf < 2; ++rf)
#pragma unroll
    for (int r = 0; r < 4; ++r) {
      float m = -1e30f;
#pragma unroll
      for (int cf = 0; cf < 16; ++cf) m = fmaxf(m, accs[rf][cf][r]);
#pragma unroll
      for (int off = 1; off < 16; off <<= 1) m = fmaxf(m, __shfl_xor(m, off, 64));
      float s = 0.f;
#pragma unroll
      for (int cf = 0; cf < 16; ++cf) {
        float p = __expf(accs[rf][cf][r] - m);
        accs[rf][cf][r] = p;
        s += p;
      }
#pragma unroll
      for (int off = 1; off < 16; off <<= 1) s += __shfl_xor(s, off, 64);
      pinv[rf][r] = 1.0f / s;
    }

  __syncthreads();   // all waves done reading k_s; safe to overwrite with P

  // PV: out = P . V, P staged per-wave through LDS (k_s region) in 64-key chunks
  f32x4 acco[2][4];
#pragma unroll
  for (int a = 0; a < 2; ++a)
#pragma unroll
    for (int c2 = 0; c2 < 4; ++c2) acco[a][c2] = fz;

  for (int ch = 0; ch < 4; ++ch) {
#pragma unroll
    for (int rf = 0; rf < 2; ++rf)
#pragma unroll
      for (int cl = 0; cl < 4; ++cl)
#pragma unroll
        for (int r = 0; r < 4; ++r) {
          int rowl = rf * 16 + lg * 4 + r;
          int ml = cl * 16 + l15;
          float p = accs[rf][ch * 4 + cl][r] * pinv[rf][r];
          *(short*)(P_s + rowl * 128 + ((ml * 2) ^ ((rowl & 7) << 4))) = (short)f2bf(p);
        }
#pragma unroll
    for (int ks = 0; ks < 2; ++ks) {
      bf16x8 pa[2];
#pragma unroll
      for (int rf = 0; rf < 2; ++rf) {
        int row = rf * 16 + l15;
        pa[rf] = *(const bf16x8*)(P_s + row * 128 + ((lg * 16 + ks * 64) ^ ((row & 7) << 4)));
      }
      int keyb = (ch * 64 + ks * 32 + lg * 8) * 2;
      __builtin_amdgcn_s_setprio(1);
#pragma unroll
      for (int df = 0; df < 4; ++df) {
        int d = df * 16 + l15;
        int term = (((d & 7) ^ ((d >> 3) & 7)) << 4);
        bf16x8 vf = *(const bf16x8*)(v_s + d * 512 + (keyb ^ term));
        acco[0][df] = __builtin_amdgcn_mfma_f32_16x16x32_bf16(pa[0], vf, acco[0][df], 0, 0, 0);
        acco[1][df] = __builtin_amdgcn_mfma_f32_16x16x32_bf16(pa[1], vf, acco[1][df], 0, 0, 0);
      }
      __builtin_amdgcn_s_setprio(0);
    }
  }

  // write attn output in (b, n, h*64+d) bf16
#pragma unroll
  for (int rf = 0; rf < 2; ++rf)
#pragma unroll
    for (int df = 0; df < 4; ++df)
#pragma unroll
      for (int r = 0; r < 4; ++r) {
        int n = w * 32 + rf * 16 + lg * 4 + r;
        int d = df * 16 + l15;
        aout[((size_t)(b * SEQ + n)) * DIM + h * HDIM + d] = f2bf(acco[rf][df][r]);
      }
}

// ---------------- launch ----------------

extern "C" void kernel_launch(void* const* d_in, const int* in_sizes, int n_in,
                              void* d_out, int out_size, void* d_ws, size_t ws_size,
                              hipStream_t stream) {
  const float* x      = (const float*)d_in[0];
  const int*   rpi    = (const int*)d_in[1];
  const float* qkv_w  = (const float*)d_in[2];
  const float* qkv_b  = (const float*)d_in[3];
  const float* proj_w = (const float*)d_in[4];
  const float* proj_b = (const float*)d_in[5];
  const float* rpb    = (const float*)d_in[6];

  char* ws = (char*)d_ws;
  unsigned short* xb    = (unsigned short*)ws;                  // 16,777,216 B
  unsigned short* wqkv  = (unsigned short*)(ws + 16777216);     //  1,572,864 B
  unsigned short* wproj = (unsigned short*)(ws + 18350080);     //    524,288 B
  float*          biasf = (float*)         (ws + 18874368);     //  2,097,152 B
  unsigned short* qkvb  = (unsigned short*)(ws + 20971520);     // 50,331,648 B (q,k,v)
  unsigned short* aoutb = (unsigned short*)(ws + 71303168);     // 16,777,216 B
  // total ws use: 88,080,384 B

  cast_kernel<<<8192, 256, 0, stream>>>(x, xb, 2097152);
  cast_kernel<<<768, 256, 0, stream>>>(qkv_w, wqkv, 196608);
  cast_kernel<<<256, 256, 0, stream>>>(proj_w, wproj, 65536);
  bias_kernel<<<2048, 256, 0, stream>>>(rpi, rpb, biasf);

  dim3 g1(128, 12);
  gemm_bt<0><<<g1, 256, 0, stream>>>(xb, wqkv, qkv_b, (void*)qkvb);

  attn_kernel<<<512, 512, 65536, stream>>>(qkvb, qkvb + BHND, qkvb + 2 * (size_t)BHND,
                                           biasf, aoutb);

  dim3 g2(128, 4);
  gemm_bt<1><<<g2, 256, 0, stream>>>(aoutb, wproj, proj_b, d_out);
}

// Round 6
// 108.563 us; speedup vs baseline: 2.2084x; 1.0180x over previous
//
#include <hip/hip_runtime.h>
#include <stdint.h>

#define DIM 512
#define NHEADS 8
#define HDIM 64
#define NBINS 961
#define BATCH 64
#define SEQ 256
#define NTOK (BATCH*SEQ)            // 16384
#define BHND (BATCH*NHEADS*SEQ*HDIM) // 8388608 elements per q/k/v tensor

using bf16x8 = __attribute__((ext_vector_type(8))) short;
using f32x4  = __attribute__((ext_vector_type(4))) float;

__device__ __forceinline__ unsigned short f2bf(float f) {
  unsigned u = __float_as_uint(f);
  u += 0x7FFF + ((u >> 16) & 1);   // round-to-nearest-even
  return (unsigned short)(u >> 16);
}

__device__ __forceinline__ void async16(const void* g, void* lds) {
  __builtin_amdgcn_global_load_lds(
      (const __attribute__((address_space(1))) unsigned int*)g,
      (__attribute__((address_space(3))) unsigned int*)lds,
      16, 0, 0);
}

// ---------------- prep kernels ----------------

__global__ void cast_kernel(const float* __restrict__ in,
                            unsigned short* __restrict__ out, int n4) {
  int i = blockIdx.x * 256 + threadIdx.x;
  if (i >= n4) return;
  float4 f = reinterpret_cast<const float4*>(in)[i];
  ushort4 o;
  o.x = f2bf(f.x); o.y = f2bf(f.y); o.z = f2bf(f.z); o.w = f2bf(f.w);
  reinterpret_cast<ushort4*>(out)[i] = o;
}

// bias stored PERMUTED: pos = h*65536 + n*256 + (m&15)*16 + (m>>4)
__global__ void bias_kernel(const int* __restrict__ idx,
                            const float* __restrict__ rpb,
                            float* __restrict__ bf) {
  int i = blockIdx.x * 256 + threadIdx.x;   // [0, 8*65536)
  if (i >= NHEADS * SEQ * SEQ) return;
  int h = i >> 16;
  int r = i & 65535;
  int n = r >> 8, m = r & 255;
  bf[(size_t)h * 65536 + n * 256 + (m & 15) * 16 + (m >> 4)] = rpb[h * NBINS + idx[r]];
}

// ---------------- 8-phase-style GEMM: C = A(Mx512) * B^T(BNx512) + bias -----
// BM=256, BK=64, 8 waves (2M x NBW*16 N each... wave tile 128 x NBW*16).
// Double-buffered LDS; ONE barrier + ONE counted vmcnt(4) per K-tile;
// stages for tile T+1 issued during tile T (A at head, B at ph1/ph2).
// XOR-(row&7) chunk swizzle on global source + LDS read (both-sides).
// EPI 0: scatter into q/k/v (B,H,N,D) bf16.  EPI 1: fp32 out row-major + bias.

__device__ __forceinline__ void stage_half(const unsigned short* __restrict__ X,
                                           int row0, int kk, char* dst, int t) {
  // one 16 KB half-tile: rows row0..row0+127, k cols kk..kk+63 (bf16)
#pragma unroll
  for (int i = 0; i < 2; ++i) {
    int q = i * 512 + t;                 // 16B chunk id 0..1023
    int r = q >> 3, s = q & 7;
    const unsigned short* src = X + (size_t)(row0 + r) * 512 + kk + ((s ^ (r & 7)) << 3);
    async16(src, dst + (size_t)(i * 512 + ((t >> 6) << 6)) * 16);
  }
}

template<int NBW, int EPI>   // NBW = B frags per wave: 4 -> BN=256, 2 -> BN=128
__global__ __launch_bounds__(512) void gemm8p(
    const unsigned short* __restrict__ A,
    const unsigned short* __restrict__ Bw,
    const float* __restrict__ bias,
    void* __restrict__ outp, int nbn, int cpx) {
  extern __shared__ char gsm[];
  constexpr int BN   = NBW * 64;
  constexpr int BUF  = 32768 + NBW * 8192;   // A 32KB + B (BN*128 B)
  const int t = threadIdx.x;
  const int lane = t & 63, l15 = lane & 15, lg = lane >> 4;
  const int wv = t >> 6, wm = wv & 1, wn = wv >> 1;
  const int bid = blockIdx.x;
  const int nid = (bid & 7) * cpx + (bid >> 3);       // XCD-chunked, bijective
  const int m0 = (nid / nbn) * 256, n0 = (nid % nbn) * BN;

  f32x4 acc[8][NBW];
  const f32x4 fz = {0.f, 0.f, 0.f, 0.f};
#pragma unroll
  for (int a = 0; a < 8; ++a)
#pragma unroll
    for (int b = 0; b < NBW; ++b) acc[a][b] = fz;

  // prologue: all units of K-tile 0 into buf 0
  stage_half(A,  m0,       0, gsm,          t);
  stage_half(A,  m0 + 128, 0, gsm + 16384,  t);
  stage_half(Bw, n0,       0, gsm + 32768,  t);
  if (NBW == 4) stage_half(Bw, n0 + 128, 0, gsm + 49152, t);

  int cur = 0;
#pragma unroll 1
  for (int T = 0; T < 8; ++T) {
    char* Ab  = gsm + cur * BUF;
    char* Bb  = Ab + 32768;
    char* nxt = gsm + (cur ^ 1) * BUF;

    __builtin_amdgcn_s_barrier();        // all waves done reading buf^1 (tile T-1)
    if (T < 7) {
      stage_half(A, m0,       (T + 1) * 64, nxt,         t);
      stage_half(A, m0 + 128, (T + 1) * 64, nxt + 16384, t);
      asm volatile("s_waitcnt vmcnt(4)" ::: "memory");   // tile T fully resident
    } else {
      asm volatile("s_waitcnt vmcnt(0)" ::: "memory");
    }
    __builtin_amdgcn_sched_barrier(0);

#pragma unroll
    for (int ph = 0; ph < 4; ++ph) {
      const int kh = ph >> 1, mh = ph & 1;
      if (ph == 1 && T < 7) stage_half(Bw, n0, (T + 1) * 64, nxt + 32768, t);
      if (NBW == 4 && ph == 2 && T < 7) stage_half(Bw, n0 + 128, (T + 1) * 64, nxt + 49152, t);

      const int sw = ((kh * 4 + lg) ^ (l15 & 7)) * 16;
      bf16x8 av[4], bv[NBW];
#pragma unroll
      for (int mi = 0; mi < 4; ++mi)
        av[mi] = *(const bf16x8*)(Ab + wm * 16384 + (mh * 64 + mi * 16 + l15) * 128 + sw);
#pragma unroll
      for (int ni = 0; ni < NBW; ++ni) {
        int rb = wn * (NBW * 16) + ni * 16 + l15;       // B row (= C col) in tile
        bv[ni] = *(const bf16x8*)(Bb + (rb >> 7) * 16384 + (rb & 127) * 128 + sw);
      }
      asm volatile("s_waitcnt lgkmcnt(0)" ::: "memory");
      __builtin_amdgcn_sched_barrier(0);
      __builtin_amdgcn_s_setprio(1);
#pragma unroll
      for (int mi = 0; mi < 4; ++mi)
#pragma unroll
        for (int ni = 0; ni < NBW; ++ni)
          acc[mh * 4 + mi][ni] =
              __builtin_amdgcn_mfma_f32_16x16x32_bf16(av[mi], bv[ni], acc[mh * 4 + mi][ni], 0, 0, 0);
      __builtin_amdgcn_s_setprio(0);
      __builtin_amdgcn_sched_barrier(0);
    }
    cur ^= 1;
  }

#pragma unroll
  for (int MI = 0; MI < 8; ++MI)
#pragma unroll
    for (int ni = 0; ni < NBW; ++ni)
#pragma unroll
      for (int r = 0; r < 4; ++r) {
        int row = m0 + wm * 128 + MI * 16 + lg * 4 + r;
        int col = n0 + wn * (NBW * 16) + ni * 16 + l15;
        float v = acc[MI][ni][r] + bias[col];
        if (EPI == 0) {
          int which = col >> 9, hd = col & 511;
          int b = row >> 8, n = row & 255;
          ((unsigned short*)outp)[(size_t)which * BHND +
              (((size_t)(b * NHEADS + (hd >> 6)) * SEQ + n) * HDIM) + (hd & 63)] = f2bf(v);
        } else {
          ((float*)outp)[(size_t)row * 512 + col] = v;
        }
      }
}

// ---------------- fused attention ----------------
// 4 waves x 16 query rows = 64 rows/block; 4 blocks per (b,h); grid 2048.
// K (32KB, XOR swizzle) + V^T (32KB) in LDS; P reuses K region after QK^T.
// XCD-chunked swizzle keeps all 4 quarters of a bh on one XCD (K/V L2 reuse).

__global__ __launch_bounds__(256) void attn_kernel(
    const unsigned short* __restrict__ qb,
    const unsigned short* __restrict__ kb,
    const unsigned short* __restrict__ vb,
    const float* __restrict__ biasf,
    unsigned short* __restrict__ aout) {
  extern __shared__ char smem[];
  char* k_s = smem;               // 32 KB: [256 keys][64 d] bf16, XOR-swizzled rows
  char* v_s = smem + 32768;       // 32 KB: vT [64 d][256 keys] bf16, key+dhi swizzle
  const int t = threadIdx.x, lane = t & 63, w = t >> 6;
  const int l15 = lane & 15, lg = lane >> 4;
  char* P_s = smem + w * 2048;    // per-wave [16 rows][64 keys] bf16 — reuses k_s
  const int nid = (blockIdx.x & 7) * 256 + (blockIdx.x >> 3);
  const int bh = nid >> 2, quarter = nid & 3;
  const int h = bh & 7;
  const int b = bh >> 3;
  const int row0 = quarter * 64 + w * 16;           // this wave's 16 query rows
  const size_t base = (size_t)bh * (SEQ * HDIM);

  // stage K (swizzled row-major)
#pragma unroll
  for (int i = 0; i < 8; ++i) {
    int c = i * 256 + t;            // 16B chunk, 2048 total
    int row = c >> 3, sl = c & 7;
    bf16x8 val = *(const bf16x8*)(kb + base + (size_t)c * 8);
    *(bf16x8*)(k_s + row * 128 + ((sl * 16) ^ ((row & 7) << 4))) = val;
  }
  // stage V transposed (vT[d][key]); swizzle spreads banks over key AND d>>3
#pragma unroll
  for (int i = 0; i < 8; ++i) {
    int c = i * 256 + t;
    int key = c >> 3, d0 = (c & 7) * 8;
    bf16x8 val = *(const bf16x8*)(vb + base + (size_t)c * 8);
#pragma unroll
    for (int j = 0; j < 8; ++j) {
      int d = d0 + j;
      int term = (((d & 7) ^ ((d >> 3) & 7)) << 4);
      *(short*)(v_s + d * 512 + ((key * 2) ^ term)) = val[j];
    }
  }
  // q fragments straight from global (L2-resident)
  bf16x8 qa[2];
#pragma unroll
  for (int ks = 0; ks < 2; ++ks)
    qa[ks] = *(const bf16x8*)(qb + base + (size_t)(row0 + l15) * 64 + ks * 32 + lg * 8);
  __syncthreads();

  // scores: S = q . k^T   (wave owns 16 query rows x 256 keys)
  f32x4 accs[16];
  const f32x4 fz = {0.f, 0.f, 0.f, 0.f};
#pragma unroll
  for (int c = 0; c < 16; ++c) accs[c] = fz;
  __builtin_amdgcn_s_setprio(1);
#pragma unroll
  for (int cf = 0; cf < 16; ++cf) {
    int key = cf * 16 + l15;
#pragma unroll
    for (int ks = 0; ks < 2; ++ks) {
      bf16x8 kf = *(const bf16x8*)(k_s + key * 128 + ((lg * 16 + ks * 64) ^ ((key & 7) << 4)));
      accs[cf] = __builtin_amdgcn_mfma_f32_16x16x32_bf16(qa[ks], kf, accs[cf], 0, 0, 0);
    }
  }
  __builtin_amdgcn_s_setprio(0);

  // scale + rel-pos bias (permuted layout -> 4x float4 per row)
  const float* bh_ptr = biasf + (size_t)h * 65536;
#pragma unroll
  for (int r = 0; r < 4; ++r) {
    int n = row0 + lg * 4 + r;
    const f32x4* bp = (const f32x4*)(bh_ptr + n * 256 + l15 * 16);
    f32x4 b0 = bp[0], b1 = bp[1], b2 = bp[2], b3 = bp[3];
#pragma unroll
    for (int cf = 0; cf < 16; ++cf) {
      float bb = (cf < 4) ? b0[cf] : (cf < 8) ? b1[cf - 4] : (cf < 12) ? b2[cf - 8] : b3[cf - 12];
      accs[cf][r] = accs[cf][r] * 0.125f + bb;
    }
  }

  // softmax across 256 keys (16 in-lane x 16 lanes)
  float pinv[4];
#pragma unroll
  for (int r = 0; r < 4; ++r) {
    float m = -1e30f;
#pragma unroll
    for (int cf = 0; cf < 16; ++cf) m = fmaxf(m, accs[cf][r]);
#pragma unroll
    for (int off = 1; off < 16; off <<= 1) m = fmaxf(m, __shfl_xor(m, off, 64));
    float s = 0.f;
#pragma unroll
    for (int cf = 0; cf < 16; ++cf) {
      float p = __expf(accs[cf][r] - m);
      accs[cf][r] = p;
      s += p;
    }
#pragma unroll
    for (int off = 1; off < 16; off <<= 1) s += __shfl_xor(s, off, 64);
    pinv[r] = 1.0f / s;
  }

  __syncthreads();   // all waves done reading k_s; safe to overwrite with P

  // PV: out = P . V, P staged per-wave through LDS (k_s region) in 64-key chunks
  f32x4 acco[4];
#pragma unroll
  for (int c2 = 0; c2 < 4; ++c2) acco[c2] = fz;

  for (int ch = 0; ch < 4; ++ch) {
#pragma unroll
    for (int cl = 0; cl < 4; ++cl)
#pragma unroll
      for (int r = 0; r < 4; ++r) {
        int rowl = lg * 4 + r;
        int ml = cl * 16 + l15;
        float p = accs[ch * 4 + cl][r] * pinv[r];
        *(short*)(P_s + rowl * 128 + ((ml * 2) ^ ((rowl & 7) << 4))) = (short)f2bf(p);
      }
#pragma unroll
    for (int ks = 0; ks < 2; ++ks) {
      bf16x8 pa = *(const bf16x8*)(P_s + l15 * 128 + ((lg * 16 + ks * 64) ^ ((l15 & 7) << 4)));
      int keyb = (ch * 64 + ks * 32 + lg * 8) * 2;
      __builtin_amdgcn_s_setprio(1);
#pragma unroll
      for (int df = 0; df < 4; ++df) {
        int d = df * 16 + l15;
        int term = (((d & 7) ^ ((d >> 3) & 7)) << 4);
        bf16x8 vf = *(const bf16x8*)(v_s + d * 512 + (keyb ^ term));
        acco[df] = __builtin_amdgcn_mfma_f32_16x16x32_bf16(pa, vf, acco[df], 0, 0, 0);
      }
      __builtin_amdgcn_s_setprio(0);
    }
  }

  // write attn output in (b, n, h*64+d) bf16
#pragma unroll
  for (int df = 0; df < 4; ++df)
#pragma unroll
    for (int r = 0; r < 4; ++r) {
      int n = row0 + lg * 4 + r;
      int d = df * 16 + l15;
      aout[((size_t)(b * SEQ + n)) * DIM + h * HDIM + d] = f2bf(acco[df][r]);
    }
}

// ---------------- launch ----------------

extern "C" void kernel_launch(void* const* d_in, const int* in_sizes, int n_in,
                              void* d_out, int out_size, void* d_ws, size_t ws_size,
                              hipStream_t stream) {
  const float* x      = (const float*)d_in[0];
  const int*   rpi    = (const int*)d_in[1];
  const float* qkv_w  = (const float*)d_in[2];
  const float* qkv_b  = (const float*)d_in[3];
  const float* proj_w = (const float*)d_in[4];
  const float* proj_b = (const float*)d_in[5];
  const float* rpb    = (const float*)d_in[6];

  char* ws = (char*)d_ws;
  unsigned short* xb    = (unsigned short*)ws;                  // 16,777,216 B
  unsigned short* wqkv  = (unsigned short*)(ws + 16777216);     //  1,572,864 B
  unsigned short* wproj = (unsigned short*)(ws + 18350080);     //    524,288 B
  float*          biasf = (float*)         (ws + 18874368);     //  2,097,152 B
  unsigned short* qkvb  = (unsigned short*)(ws + 20971520);     // 50,331,648 B (q,k,v)
  unsigned short* aoutb = (unsigned short*)(ws + 71303168);     // 16,777,216 B
  // total ws use: 88,080,384 B

  cast_kernel<<<8192, 256, 0, stream>>>(x, xb, 2097152);
  cast_kernel<<<768, 256, 0, stream>>>(qkv_w, wqkv, 196608);
  cast_kernel<<<256, 256, 0, stream>>>(proj_w, wproj, 65536);
  bias_kernel<<<2048, 256, 0, stream>>>(rpi, rpb, biasf);

  // QKV GEMM: M=16384, N=1536 -> 64 x 6 = 384 blocks, BN=256
  gemm8p<4, 0><<<384, 512, 131072, stream>>>(xb, wqkv, qkv_b, (void*)qkvb, 6, 48);

  attn_kernel<<<2048, 256, 65536, stream>>>(qkvb, qkvb + BHND, qkvb + 2 * (size_t)BHND,
                                            biasf, aoutb);

  // proj GEMM: M=16384, N=512 -> 64 x 4 = 256 blocks, BN=128
  gemm8p<2, 1><<<256, 512, 98304, stream>>>(aoutb, wproj, proj_b, d_out, 4, 32);
}